// Round 10
// baseline (3089.790 us; speedup 1.0000x reference)
//
#include <hip/hip_runtime.h>
#include <hip/hip_bf16.h>

#define T_TOK 8192
#define DDIM  1024
#define HDIM  4096
#define KCAT  8192   // 2*HDIM
#define NE    8

typedef __attribute__((ext_vector_type(8))) __bf16 bf16x8;
typedef __attribute__((ext_vector_type(4))) float  f32x4;

__device__ __forceinline__ unsigned short f2bf(float f) {
  union { float f; unsigned u; } v; v.f = f;
  unsigned r = v.u + 0x7fffu + ((v.u >> 16) & 1u);
  return (unsigned short)(r >> 16);
}

__device__ __forceinline__ void gl_lds16(const unsigned short* g, char* l) {
  __builtin_amdgcn_global_load_lds(
      (__attribute__((address_space(1))) const void*)g,
      (__attribute__((address_space(3))) void*)l,
      16, 0, 0);
}

// ---------------- router + x -> bf16 conversion ----------------
__global__ __launch_bounds__(256) void k_router(
    const float* __restrict__ x, const float* __restrict__ Wr,
    const float* __restrict__ br, unsigned short* __restrict__ xb,
    float* __restrict__ gates)
{
  const int lane = threadIdx.x & 63;
  const int wv   = threadIdx.x >> 6;
  const int t    = blockIdx.x * 4 + wv;
  const float* xr = x + (size_t)t * DDIM;
  unsigned short* xo = xb + (size_t)t * DDIM;

  float acc[NE];
#pragma unroll
  for (int e = 0; e < NE; ++e) acc[e] = 0.f;

#pragma unroll
  for (int i = 0; i < 4; ++i) {
    float4 v = *(const float4*)(xr + i * 256 + lane * 4);
    ushort4 o;
    o.x = f2bf(v.x); o.y = f2bf(v.y); o.z = f2bf(v.z); o.w = f2bf(v.w);
    *(ushort4*)(xo + i * 256 + lane * 4) = o;
    float vs[4] = {v.x, v.y, v.z, v.w};
#pragma unroll
    for (int j = 0; j < 4; ++j) {
      const float4* wr = (const float4*)(Wr + (size_t)(i * 256 + lane * 4 + j) * NE);
      float4 w0 = wr[0], w1 = wr[1];
      acc[0] += vs[j] * w0.x; acc[1] += vs[j] * w0.y;
      acc[2] += vs[j] * w0.z; acc[3] += vs[j] * w0.w;
      acc[4] += vs[j] * w1.x; acc[5] += vs[j] * w1.y;
      acc[6] += vs[j] * w1.z; acc[7] += vs[j] * w1.w;
    }
  }
#pragma unroll
  for (int e = 0; e < NE; ++e) {
#pragma unroll
    for (int s = 32; s > 0; s >>= 1) acc[e] += __shfl_xor(acc[e], s, 64);
  }
  if (lane == 0) {
    float lg[NE];
#pragma unroll
    for (int e = 0; e < NE; ++e) lg[e] = acc[e] + br[e];
    int a1 = 0; float m1 = lg[0];
#pragma unroll
    for (int e = 1; e < NE; ++e) if (lg[e] > m1) { m1 = lg[e]; a1 = e; }
    float m2 = -3.4e38f;
#pragma unroll
    for (int e = 0; e < NE; ++e) if (e != a1 && lg[e] > m2) m2 = lg[e];
    float g0 = 1.f / (1.f + expf(m2 - m1));
    gates[t * 2 + 0] = g0;
    gates[t * 2 + 1] = 1.f - g0;
  }
}

// ---------------- fp32 -> bf16 transpose ----------------
__global__ __launch_bounds__(256) void k_transpose(
    const float* __restrict__ in, unsigned short* __restrict__ out,
    int R, int C, int S, size_t inz, size_t outz)
{
  __shared__ float tile[32][33];
  in  += (size_t)blockIdx.z * inz;
  out += (size_t)blockIdx.z * outz;
  const int c0 = blockIdx.x * 32, r0 = blockIdx.y * 32;
  const int tx = threadIdx.x & 31, ty = threadIdx.x >> 5;
#pragma unroll
  for (int i = 0; i < 32; i += 8)
    tile[ty + i][tx] = in[(size_t)(r0 + ty + i) * C + (c0 + tx)];
  __syncthreads();
#pragma unroll
  for (int i = 0; i < 32; i += 8)
    out[(size_t)(c0 + ty + i) * S + (r0 + tx)] = f2bf(tile[tx][ty + i]);
}

// ------------- 2-resident-block 256x256 MFMA GEMM (BK=32, 2 buffers) -------
// C[256x256 tile] = A[M][KA]·B[N][KB]^T over K = NT*32 from koff = z*NT*32.
// 512 threads = 8 waves (2M x 4N), per-wave 128x64, 16x16x32 frags.
// LDS: 2 buffers x {A 16KiB, B 16KiB} = 64 KiB -> TWO blocks per CU
// (16 waves/CU, 4/SIMD at 128 VGPR). The co-resident block's waves fill the
// MFMA pipe while this block sits at vmcnt/barrier — the m114 implicit
// overlap that every 1-block/CU schedule variant (R4-R9) lacked.
// Phase t: {vmcnt(0); bar; 12 ds_reads(buf t&1); stage t+1 -> buf^1;
//           32 MFMA; bar}. Hazards: stage(t+1) vs t-1 reads of buf^1
// separated by two barriers; data-ready by vmcnt(0)+bar at t+1.
template<int NT, int MODE>
__global__ __launch_bounds__(512, 4) void k_gemm2(
    const unsigned short* __restrict__ A,
    const unsigned short* __restrict__ B,
    unsigned short* __restrict__ Hout,
    float* __restrict__ P0, float* __restrict__ P1,
    const float* __restrict__ bias,
    const float* __restrict__ gates,
    int KA, int KB)
{
  __shared__ __align__(16) char lds[2 * 32768];

  const int tid = threadIdx.x;
  const int l = tid & 63, g = (l >> 4), l15 = l & 15;
  const int w = tid >> 6;
  const int wm = w >> 2, wn = w & 3;

  // ---- XCD-chunked bijective swizzle (kept constant since R4) ----
  int bmIdx, bnIdx, bzIdx;
  {
    int lin = ((blockIdx.z * gridDim.y) + blockIdx.y) * gridDim.x + blockIdx.x;
    int xcd = lin & 7, slot = (lin >> 3) & 31;
    if (MODE == 0) {
      int r = lin >> 8;
      bmIdx = r * 8 + (slot >> 2);
      bnIdx = xcd * 4 + (slot & 3);
      bzIdx = 0;
    } else {
      bzIdx = xcd & 1;
      bmIdx = (xcd >> 1) * 8 + (slot >> 2);
      bnIdx = slot & 3;
    }
  }
  const int bn = bnIdx * 256;
  const int bm = bmIdx * 256;
  const int koff = bzIdx * (NT * 32);

  // staging: dest chunk tid = (row=tid>>2, c=tid&3); source chunk = c ^ ((row>>1)&3)
  const int srow = tid >> 2;
  const int sc = (tid & 3) ^ ((srow >> 1) & 3);
  const unsigned short* As = A + (size_t)(bm + srow) * KA + koff + sc * 8;
  const unsigned short* Bs = B + (size_t)(bn + srow) * KB + koff + sc * 8;

  auto stage = [&](int T, int reg) {  // reg: 0=A, 1=B; tile T = k [T*32, T*32+32)
    const unsigned short* src = (reg ? Bs : As) + T * 32;
    size_t rstride = (size_t)128 * (reg ? KB : KA);
    char* dst = lds + ((T & 1) << 15) + (reg << 14) + tid * 16;
    gl_lds16(src, dst);
    gl_lds16(src + rstride, dst + 8192);
  };

  // fragment LDS byte offsets within a 16 KiB region (rows: 64 B = 32 bf16 k)
  int aoff[2][4], boff[4];
#pragma unroll
  for (int mh = 0; mh < 2; ++mh)
#pragma unroll
    for (int mi = 0; mi < 4; ++mi) {
      int r = wm * 128 + mh * 64 + mi * 16 + l15;
      aoff[mh][mi] = r * 64 + ((g ^ ((r >> 1) & 3)) * 16);
    }
#pragma unroll
  for (int nj = 0; nj < 4; ++nj) {
    int r = wn * 64 + nj * 16 + l15;
    boff[nj] = r * 64 + ((g ^ ((r >> 1) & 3)) * 16);
  }

  f32x4 acc[8][4];
#pragma unroll
  for (int i = 0; i < 8; ++i)
#pragma unroll
    for (int j = 0; j < 4; ++j) acc[i][j] = (f32x4){0.f, 0.f, 0.f, 0.f};

  // prologue: stage tile 0 into buf 0
  stage(0, 0); stage(0, 1);

#define MFMA16(AI, A0, A1, A2, A3)                                                     \
    acc[(AI)+0][0] = __builtin_amdgcn_mfma_f32_16x16x32_bf16(A0, vb0, acc[(AI)+0][0], 0,0,0); \
    acc[(AI)+0][1] = __builtin_amdgcn_mfma_f32_16x16x32_bf16(A0, vb1, acc[(AI)+0][1], 0,0,0); \
    acc[(AI)+0][2] = __builtin_amdgcn_mfma_f32_16x16x32_bf16(A0, vb2, acc[(AI)+0][2], 0,0,0); \
    acc[(AI)+0][3] = __builtin_amdgcn_mfma_f32_16x16x32_bf16(A0, vb3, acc[(AI)+0][3], 0,0,0); \
    acc[(AI)+1][0] = __builtin_amdgcn_mfma_f32_16x16x32_bf16(A1, vb0, acc[(AI)+1][0], 0,0,0); \
    acc[(AI)+1][1] = __builtin_amdgcn_mfma_f32_16x16x32_bf16(A1, vb1, acc[(AI)+1][1], 0,0,0); \
    acc[(AI)+1][2] = __builtin_amdgcn_mfma_f32_16x16x32_bf16(A1, vb2, acc[(AI)+1][2], 0,0,0); \
    acc[(AI)+1][3] = __builtin_amdgcn_mfma_f32_16x16x32_bf16(A1, vb3, acc[(AI)+1][3], 0,0,0); \
    acc[(AI)+2][0] = __builtin_amdgcn_mfma_f32_16x16x32_bf16(A2, vb0, acc[(AI)+2][0], 0,0,0); \
    acc[(AI)+2][1] = __builtin_amdgcn_mfma_f32_16x16x32_bf16(A2, vb1, acc[(AI)+2][1], 0,0,0); \
    acc[(AI)+2][2] = __builtin_amdgcn_mfma_f32_16x16x32_bf16(A2, vb2, acc[(AI)+2][2], 0,0,0); \
    acc[(AI)+2][3] = __builtin_amdgcn_mfma_f32_16x16x32_bf16(A2, vb3, acc[(AI)+2][3], 0,0,0); \
    acc[(AI)+3][0] = __builtin_amdgcn_mfma_f32_16x16x32_bf16(A3, vb0, acc[(AI)+3][0], 0,0,0); \
    acc[(AI)+3][1] = __builtin_amdgcn_mfma_f32_16x16x32_bf16(A3, vb1, acc[(AI)+3][1], 0,0,0); \
    acc[(AI)+3][2] = __builtin_amdgcn_mfma_f32_16x16x32_bf16(A3, vb2, acc[(AI)+3][2], 0,0,0); \
    acc[(AI)+3][3] = __builtin_amdgcn_mfma_f32_16x16x32_bf16(A3, vb3, acc[(AI)+3][3], 0,0,0);

  // one phase per K=32 tile
#define MPH(BUF, STG) do {                                                     \
    asm volatile("s_waitcnt vmcnt(0)" ::: "memory");                           \
    __builtin_amdgcn_s_barrier();                                              \
    const char* Ar_ = lds + ((BUF) << 15);                                     \
    const char* Br_ = Ar_ + 16384;                                             \
    bf16x8 vb0 = *(const bf16x8*)(Br_ + boff[0]);                              \
    bf16x8 vb1 = *(const bf16x8*)(Br_ + boff[1]);                              \
    bf16x8 vb2 = *(const bf16x8*)(Br_ + boff[2]);                              \
    bf16x8 vb3 = *(const bf16x8*)(Br_ + boff[3]);                              \
    bf16x8 vc0 = *(const bf16x8*)(Ar_ + aoff[0][0]);                           \
    bf16x8 vc1 = *(const bf16x8*)(Ar_ + aoff[0][1]);                           \
    bf16x8 vc2 = *(const bf16x8*)(Ar_ + aoff[0][2]);                           \
    bf16x8 vc3 = *(const bf16x8*)(Ar_ + aoff[0][3]);                           \
    bf16x8 vn0 = *(const bf16x8*)(Ar_ + aoff[1][0]);                           \
    bf16x8 vn1 = *(const bf16x8*)(Ar_ + aoff[1][1]);                           \
    bf16x8 vn2 = *(const bf16x8*)(Ar_ + aoff[1][2]);                           \
    bf16x8 vn3 = *(const bf16x8*)(Ar_ + aoff[1][3]);                           \
    asm volatile("" ::: "memory");                                             \
    STG;                                                                       \
    __builtin_amdgcn_s_setprio(1);                                             \
    MFMA16(0, vc0, vc1, vc2, vc3)                                              \
    MFMA16(4, vn0, vn1, vn2, vn3)                                              \
    __builtin_amdgcn_s_setprio(0);                                             \
    __builtin_amdgcn_s_barrier();                                              \
  } while (0)

  // main loop: phases t = 0 .. NT-3 staging t+1; NT even
  for (int tt = 0; tt < NT / 2 - 1; ++tt) {
    int t2 = tt * 2;
    MPH(0, { stage(t2 + 1, 0); stage(t2 + 1, 1); });
    MPH(1, { stage(t2 + 2, 0); stage(t2 + 2, 1); });
  }
  // tail: phase NT-2 stages NT-1; phase NT-1 stages nothing
  MPH(0, { stage(NT - 1, 0); stage(NT - 1, 1); });
  MPH(1, ;);
#undef MPH
#undef MFMA16

  // epilogue; C/D map: col = l&15, row = (l>>4)*4 + rr
  if constexpr (MODE == 0) {
    const int ge = bn >> 12;
    float bcol[4];
#pragma unroll
    for (int nj = 0; nj < 4; ++nj) bcol[nj] = bias[bn + wn * 64 + nj * 16 + l15];
#pragma unroll
    for (int mi = 0; mi < 8; ++mi) {
#pragma unroll
      for (int rr = 0; rr < 4; ++rr) {
        int row = bm + wm * 128 + mi * 16 + g * 4 + rr;
        float gate = gates[row * 2 + ge];
        size_t rb = (size_t)row * KCAT + bn + wn * 64 + l15;
#pragma unroll
        for (int nj = 0; nj < 4; ++nj) {
          float v = acc[mi][nj][rr] + bcol[nj];
          Hout[rb + nj * 16] = f2bf(fmaxf(v, 0.f) * gate);
        }
      }
    }
  } else {
    float* P = bzIdx ? P1 : P0;
#pragma unroll
    for (int mi = 0; mi < 8; ++mi) {
#pragma unroll
      for (int rr = 0; rr < 4; ++rr) {
        int row = bm + wm * 128 + mi * 16 + g * 4 + rr;
        size_t rb = (size_t)row * DDIM + bn + wn * 64 + l15;
#pragma unroll
        for (int nj = 0; nj < 4; ++nj) P[rb + nj * 16] = acc[mi][nj][rr];
      }
    }
  }
}

// ---------------- combine: out = p0 + p1 + g0*b2[0] + g1*b2[1] ----------------
__global__ __launch_bounds__(256) void k_combine(
    const float* __restrict__ P1, const float* __restrict__ b2,
    const float* __restrict__ gates, float* __restrict__ O)
{
  size_t i = ((size_t)blockIdx.x * 256 + threadIdx.x) * 4;
  int row = (int)(i >> 10), d = (int)(i & 1023);
  float g0 = gates[row * 2], g1 = gates[row * 2 + 1];
  float4 p0 = *(const float4*)(O + i);
  float4 p1 = *(const float4*)(P1 + i);
  float4 ba = *(const float4*)(b2 + d);
  float4 bb = *(const float4*)(b2 + DDIM + d);
  float4 r;
  r.x = p0.x + p1.x + g0 * ba.x + g1 * bb.x;
  r.y = p0.y + p1.y + g0 * ba.y + g1 * bb.y;
  r.z = p0.z + p1.z + g0 * ba.z + g1 * bb.z;
  r.w = p0.w + p1.w + g0 * ba.w + g1 * bb.w;
  *(float4*)(O + i) = r;
}

extern "C" void kernel_launch(void* const* d_in, const int* in_sizes, int n_in,
                              void* d_out, int out_size, void* d_ws, size_t ws_size,
                              hipStream_t stream) {
  const float* x  = (const float*)d_in[0];
  const float* Wr = (const float*)d_in[1];
  const float* br = (const float*)d_in[2];
  const float* W1 = (const float*)d_in[3];
  const float* b1 = (const float*)d_in[4];
  const float* W2 = (const float*)d_in[5];
  const float* b2 = (const float*)d_in[6];

  char* ws = (char*)d_ws;
  unsigned short* xb    = (unsigned short*)(ws);               // [0,16M)  x bf16
  unsigned short* W1T   = (unsigned short*)(ws + (16u << 20)); // [16,32M) [8192][1024]
  unsigned short* W2T   = (unsigned short*)(ws + (32u << 20)); // [32,48M) [1024][8192]
  float*          gates = (float*)(ws + (48u << 20));          // [48M,+64K)
  unsigned short* hbuf  = (unsigned short*)(ws + (49u << 20)); // [49,177M) [8192][8192]
  float*          P1    = (float*)(ws);                        // reuses xb+W1T after GEMM1

  k_router<<<dim3(T_TOK / 4), dim3(256), 0, stream>>>(x, Wr, br, xb, gates);

  k_transpose<<<dim3(HDIM / 32, DDIM / 32, 2), dim3(256), 0, stream>>>(
      W1, W1T, DDIM, HDIM, DDIM, (size_t)DDIM * HDIM, (size_t)HDIM * DDIM);
  k_transpose<<<dim3(DDIM / 32, HDIM / 32, 2), dim3(256), 0, stream>>>(
      W2, W2T, HDIM, DDIM, KCAT, (size_t)HDIM * DDIM, (size_t)HDIM);

  // layer1: 8192x8192x1024 (experts concat over N), NT = 1024/32 = 32
  k_gemm2<32, 0><<<dim3(KCAT / 256, T_TOK / 256, 1), dim3(512), 0, stream>>>(
      xb, W1T, hbuf, nullptr, nullptr, b1, gates, DDIM, DDIM);

  // layer2: 8192x1024x8192, split-K=2 at expert boundary, NT = 4096/32 = 128
  k_gemm2<128, 1><<<dim3(DDIM / 256, T_TOK / 256, 2), dim3(512), 0, stream>>>(
      hbuf, W2T, nullptr, (float*)d_out, P1, nullptr, nullptr, KCAT, KCAT);

  k_combine<<<dim3(T_TOK * DDIM / 4 / 256), dim3(256), 0, stream>>>(
      P1, b2, gates, (float*)d_out);
}

// Round 11
// 325.430 us; speedup vs baseline: 9.4945x; 9.4945x over previous
//
#include <hip/hip_runtime.h>
#include <hip/hip_bf16.h>

#define T_TOK 8192
#define DDIM  1024
#define HDIM  4096
#define KCAT  8192   // 2*HDIM
#define NE    8

typedef __attribute__((ext_vector_type(8))) __bf16 bf16x8;
typedef __attribute__((ext_vector_type(4))) float  f32x4;

__device__ __forceinline__ unsigned short f2bf(float f) {
  union { float f; unsigned u; } v; v.f = f;
  unsigned r = v.u + 0x7fffu + ((v.u >> 16) & 1u);
  return (unsigned short)(r >> 16);
}

__device__ __forceinline__ void gl_lds16(const unsigned short* g, char* l) {
  __builtin_amdgcn_global_load_lds(
      (__attribute__((address_space(1))) const void*)g,
      (__attribute__((address_space(3))) void*)l,
      16, 0, 0);
}

// ---------------- router + x -> bf16 conversion ----------------
__global__ __launch_bounds__(256) void k_router(
    const float* __restrict__ x, const float* __restrict__ Wr,
    const float* __restrict__ br, unsigned short* __restrict__ xb,
    float* __restrict__ gates)
{
  const int lane = threadIdx.x & 63;
  const int wv   = threadIdx.x >> 6;
  const int t    = blockIdx.x * 4 + wv;
  const float* xr = x + (size_t)t * DDIM;
  unsigned short* xo = xb + (size_t)t * DDIM;

  float acc[NE];
#pragma unroll
  for (int e = 0; e < NE; ++e) acc[e] = 0.f;

#pragma unroll
  for (int i = 0; i < 4; ++i) {
    float4 v = *(const float4*)(xr + i * 256 + lane * 4);
    ushort4 o;
    o.x = f2bf(v.x); o.y = f2bf(v.y); o.z = f2bf(v.z); o.w = f2bf(v.w);
    *(ushort4*)(xo + i * 256 + lane * 4) = o;
    float vs[4] = {v.x, v.y, v.z, v.w};
#pragma unroll
    for (int j = 0; j < 4; ++j) {
      const float4* wr = (const float4*)(Wr + (size_t)(i * 256 + lane * 4 + j) * NE);
      float4 w0 = wr[0], w1 = wr[1];
      acc[0] += vs[j] * w0.x; acc[1] += vs[j] * w0.y;
      acc[2] += vs[j] * w0.z; acc[3] += vs[j] * w0.w;
      acc[4] += vs[j] * w1.x; acc[5] += vs[j] * w1.y;
      acc[6] += vs[j] * w1.z; acc[7] += vs[j] * w1.w;
    }
  }
#pragma unroll
  for (int e = 0; e < NE; ++e) {
#pragma unroll
    for (int s = 32; s > 0; s >>= 1) acc[e] += __shfl_xor(acc[e], s, 64);
  }
  if (lane == 0) {
    float lg[NE];
#pragma unroll
    for (int e = 0; e < NE; ++e) lg[e] = acc[e] + br[e];
    int a1 = 0; float m1 = lg[0];
#pragma unroll
    for (int e = 1; e < NE; ++e) if (lg[e] > m1) { m1 = lg[e]; a1 = e; }
    float m2 = -3.4e38f;
#pragma unroll
    for (int e = 0; e < NE; ++e) if (e != a1 && lg[e] > m2) m2 = lg[e];
    float g0 = 1.f / (1.f + expf(m2 - m1));
    gates[t * 2 + 0] = g0;
    gates[t * 2 + 1] = 1.f - g0;
  }
}

// ---------------- fp32 -> bf16 transpose ----------------
__global__ __launch_bounds__(256) void k_transpose(
    const float* __restrict__ in, unsigned short* __restrict__ out,
    int R, int C, int S, size_t inz, size_t outz)
{
  __shared__ float tile[32][33];
  in  += (size_t)blockIdx.z * inz;
  out += (size_t)blockIdx.z * outz;
  const int c0 = blockIdx.x * 32, r0 = blockIdx.y * 32;
  const int tx = threadIdx.x & 31, ty = threadIdx.x >> 5;
#pragma unroll
  for (int i = 0; i < 32; i += 8)
    tile[ty + i][tx] = in[(size_t)(r0 + ty + i) * C + (c0 + tx)];
  __syncthreads();
#pragma unroll
  for (int i = 0; i < 32; i += 8)
    out[(size_t)(c0 + ty + i) * S + (r0 + tx)] = f2bf(tile[tx][ty + i]);
}

// ------------- 2-resident-block 256x256 MFMA GEMM (BK=32, 2 buffers) -------
// C[256x256 tile] = A[M][KA]·B[N][KB]^T over K = NT*32 from koff = z*NT*32.
// 512 threads = 8 waves (2M x 4N), per-wave 128x64, 16x16x32 frags.
// LDS: 2 buffers x {A 16KiB, B 16KiB} = 64 KiB -> TWO blocks per CU.
// __launch_bounds__(512, 2): HIP 2nd arg = min BLOCKS per CU (CUDA semantics;
// R10's (512,4) forced 64-VGPR cap -> spill disaster). 2 blocks x 8 waves =
// 4 waves/SIMD at 128 VGPR — fits the 120-128 VGPR pressure with no spill.
// The co-resident block's waves fill the MFMA pipe while this block sits at
// vmcnt/barrier (m114 implicit overlap, absent in all 1-block/CU variants).
template<int NT, int MODE>
__global__ __launch_bounds__(512, 2) void k_gemm2(
    const unsigned short* __restrict__ A,
    const unsigned short* __restrict__ B,
    unsigned short* __restrict__ Hout,
    float* __restrict__ P0, float* __restrict__ P1,
    const float* __restrict__ bias,
    const float* __restrict__ gates,
    int KA, int KB)
{
  __shared__ __align__(16) char lds[2 * 32768];

  const int tid = threadIdx.x;
  const int l = tid & 63, g = (l >> 4), l15 = l & 15;
  const int w = tid >> 6;
  const int wm = w >> 2, wn = w & 3;

  // ---- XCD-chunked bijective swizzle (kept constant since R4) ----
  int bmIdx, bnIdx, bzIdx;
  {
    int lin = ((blockIdx.z * gridDim.y) + blockIdx.y) * gridDim.x + blockIdx.x;
    int xcd = lin & 7, slot = (lin >> 3) & 31;
    if (MODE == 0) {
      int r = lin >> 8;
      bmIdx = r * 8 + (slot >> 2);
      bnIdx = xcd * 4 + (slot & 3);
      bzIdx = 0;
    } else {
      bzIdx = xcd & 1;
      bmIdx = (xcd >> 1) * 8 + (slot >> 2);
      bnIdx = slot & 3;
    }
  }
  const int bn = bnIdx * 256;
  const int bm = bmIdx * 256;
  const int koff = bzIdx * (NT * 32);

  // staging: dest chunk tid = (row=tid>>2, c=tid&3); source chunk = c ^ ((row>>1)&3)
  const int srow = tid >> 2;
  const int sc = (tid & 3) ^ ((srow >> 1) & 3);
  const unsigned short* As = A + (size_t)(bm + srow) * KA + koff + sc * 8;
  const unsigned short* Bs = B + (size_t)(bn + srow) * KB + koff + sc * 8;

  auto stage = [&](int T, int reg) {  // reg: 0=A, 1=B; tile T = k [T*32, T*32+32)
    const unsigned short* src = (reg ? Bs : As) + T * 32;
    size_t rstride = (size_t)128 * (reg ? KB : KA);
    char* dst = lds + ((T & 1) << 15) + (reg << 14) + tid * 16;
    gl_lds16(src, dst);
    gl_lds16(src + rstride, dst + 8192);
  };

  // fragment LDS byte offsets within a 16 KiB region (rows: 64 B = 32 bf16 k)
  int aoff[2][4], boff[4];
#pragma unroll
  for (int mh = 0; mh < 2; ++mh)
#pragma unroll
    for (int mi = 0; mi < 4; ++mi) {
      int r = wm * 128 + mh * 64 + mi * 16 + l15;
      aoff[mh][mi] = r * 64 + ((g ^ ((r >> 1) & 3)) * 16);
    }
#pragma unroll
  for (int nj = 0; nj < 4; ++nj) {
    int r = wn * 64 + nj * 16 + l15;
    boff[nj] = r * 64 + ((g ^ ((r >> 1) & 3)) * 16);
  }

  f32x4 acc[8][4];
#pragma unroll
  for (int i = 0; i < 8; ++i)
#pragma unroll
    for (int j = 0; j < 4; ++j) acc[i][j] = (f32x4){0.f, 0.f, 0.f, 0.f};

  // prologue: stage tile 0 into buf 0
  stage(0, 0); stage(0, 1);

#define MFMA16(AI, A0, A1, A2, A3)                                                     \
    acc[(AI)+0][0] = __builtin_amdgcn_mfma_f32_16x16x32_bf16(A0, vb0, acc[(AI)+0][0], 0,0,0); \
    acc[(AI)+0][1] = __builtin_amdgcn_mfma_f32_16x16x32_bf16(A0, vb1, acc[(AI)+0][1], 0,0,0); \
    acc[(AI)+0][2] = __builtin_amdgcn_mfma_f32_16x16x32_bf16(A0, vb2, acc[(AI)+0][2], 0,0,0); \
    acc[(AI)+0][3] = __builtin_amdgcn_mfma_f32_16x16x32_bf16(A0, vb3, acc[(AI)+0][3], 0,0,0); \
    acc[(AI)+1][0] = __builtin_amdgcn_mfma_f32_16x16x32_bf16(A1, vb0, acc[(AI)+1][0], 0,0,0); \
    acc[(AI)+1][1] = __builtin_amdgcn_mfma_f32_16x16x32_bf16(A1, vb1, acc[(AI)+1][1], 0,0,0); \
    acc[(AI)+1][2] = __builtin_amdgcn_mfma_f32_16x16x32_bf16(A1, vb2, acc[(AI)+1][2], 0,0,0); \
    acc[(AI)+1][3] = __builtin_amdgcn_mfma_f32_16x16x32_bf16(A1, vb3, acc[(AI)+1][3], 0,0,0); \
    acc[(AI)+2][0] = __builtin_amdgcn_mfma_f32_16x16x32_bf16(A2, vb0, acc[(AI)+2][0], 0,0,0); \
    acc[(AI)+2][1] = __builtin_amdgcn_mfma_f32_16x16x32_bf16(A2, vb1, acc[(AI)+2][1], 0,0,0); \
    acc[(AI)+2][2] = __builtin_amdgcn_mfma_f32_16x16x32_bf16(A2, vb2, acc[(AI)+2][2], 0,0,0); \
    acc[(AI)+2][3] = __builtin_amdgcn_mfma_f32_16x16x32_bf16(A2, vb3, acc[(AI)+2][3], 0,0,0); \
    acc[(AI)+3][0] = __builtin_amdgcn_mfma_f32_16x16x32_bf16(A3, vb0, acc[(AI)+3][0], 0,0,0); \
    acc[(AI)+3][1] = __builtin_amdgcn_mfma_f32_16x16x32_bf16(A3, vb1, acc[(AI)+3][1], 0,0,0); \
    acc[(AI)+3][2] = __builtin_amdgcn_mfma_f32_16x16x32_bf16(A3, vb2, acc[(AI)+3][2], 0,0,0); \
    acc[(AI)+3][3] = __builtin_amdgcn_mfma_f32_16x16x32_bf16(A3, vb3, acc[(AI)+3][3], 0,0,0);

  // one phase per K=32 tile
#define MPH(BUF, STG) do {                                                     \
    asm volatile("s_waitcnt vmcnt(0)" ::: "memory");                           \
    __builtin_amdgcn_s_barrier();                                              \
    const char* Ar_ = lds + ((BUF) << 15);                                     \
    const char* Br_ = Ar_ + 16384;                                             \
    bf16x8 vb0 = *(const bf16x8*)(Br_ + boff[0]);                              \
    bf16x8 vb1 = *(const bf16x8*)(Br_ + boff[1]);                              \
    bf16x8 vb2 = *(const bf16x8*)(Br_ + boff[2]);                              \
    bf16x8 vb3 = *(const bf16x8*)(Br_ + boff[3]);                              \
    bf16x8 vc0 = *(const bf16x8*)(Ar_ + aoff[0][0]);                           \
    bf16x8 vc1 = *(const bf16x8*)(Ar_ + aoff[0][1]);                           \
    bf16x8 vc2 = *(const bf16x8*)(Ar_ + aoff[0][2]);                           \
    bf16x8 vc3 = *(const bf16x8*)(Ar_ + aoff[0][3]);                           \
    bf16x8 vn0 = *(const bf16x8*)(Ar_ + aoff[1][0]);                           \
    bf16x8 vn1 = *(const bf16x8*)(Ar_ + aoff[1][1]);                           \
    bf16x8 vn2 = *(const bf16x8*)(Ar_ + aoff[1][2]);                           \
    bf16x8 vn3 = *(const bf16x8*)(Ar_ + aoff[1][3]);                           \
    asm volatile("" ::: "memory");                                             \
    STG;                                                                       \
    __builtin_amdgcn_s_setprio(1);                                             \
    MFMA16(0, vc0, vc1, vc2, vc3)                                              \
    MFMA16(4, vn0, vn1, vn2, vn3)                                              \
    __builtin_amdgcn_s_setprio(0);                                             \
    __builtin_amdgcn_s_barrier();                                              \
  } while (0)

  // main loop: phases t = 0 .. NT-3 staging t+1; NT even
  for (int tt = 0; tt < NT / 2 - 1; ++tt) {
    int t2 = tt * 2;
    MPH(0, { stage(t2 + 1, 0); stage(t2 + 1, 1); });
    MPH(1, { stage(t2 + 2, 0); stage(t2 + 2, 1); });
  }
  // tail: phase NT-2 stages NT-1; phase NT-1 stages nothing
  MPH(0, { stage(NT - 1, 0); stage(NT - 1, 1); });
  MPH(1, ;);
#undef MPH
#undef MFMA16

  // epilogue; C/D map: col = l&15, row = (l>>4)*4 + rr
  if constexpr (MODE == 0) {
    const int ge = bn >> 12;
    float bcol[4];
#pragma unroll
    for (int nj = 0; nj < 4; ++nj) bcol[nj] = bias[bn + wn * 64 + nj * 16 + l15];
#pragma unroll
    for (int mi = 0; mi < 8; ++mi) {
#pragma unroll
      for (int rr = 0; rr < 4; ++rr) {
        int row = bm + wm * 128 + mi * 16 + g * 4 + rr;
        float gate = gates[row * 2 + ge];
        size_t rb = (size_t)row * KCAT + bn + wn * 64 + l15;
#pragma unroll
        for (int nj = 0; nj < 4; ++nj) {
          float v = acc[mi][nj][rr] + bcol[nj];
          Hout[rb + nj * 16] = f2bf(fmaxf(v, 0.f) * gate);
        }
      }
    }
  } else {
    float* P = bzIdx ? P1 : P0;
#pragma unroll
    for (int mi = 0; mi < 8; ++mi) {
#pragma unroll
      for (int rr = 0; rr < 4; ++rr) {
        int row = bm + wm * 128 + mi * 16 + g * 4 + rr;
        size_t rb = (size_t)row * DDIM + bn + wn * 64 + l15;
#pragma unroll
        for (int nj = 0; nj < 4; ++nj) P[rb + nj * 16] = acc[mi][nj][rr];
      }
    }
  }
}

// ---------------- combine: out = p0 + p1 + g0*b2[0] + g1*b2[1] ----------------
__global__ __launch_bounds__(256) void k_combine(
    const float* __restrict__ P1, const float* __restrict__ b2,
    const float* __restrict__ gates, float* __restrict__ O)
{
  size_t i = ((size_t)blockIdx.x * 256 + threadIdx.x) * 4;
  int row = (int)(i >> 10), d = (int)(i & 1023);
  float g0 = gates[row * 2], g1 = gates[row * 2 + 1];
  float4 p0 = *(const float4*)(O + i);
  float4 p1 = *(const float4*)(P1 + i);
  float4 ba = *(const float4*)(b2 + d);
  float4 bb = *(const float4*)(b2 + DDIM + d);
  float4 r;
  r.x = p0.x + p1.x + g0 * ba.x + g1 * bb.x;
  r.y = p0.y + p1.y + g0 * ba.y + g1 * bb.y;
  r.z = p0.z + p1.z + g0 * ba.z + g1 * bb.z;
  r.w = p0.w + p1.w + g0 * ba.w + g1 * bb.w;
  *(float4*)(O + i) = r;
}

extern "C" void kernel_launch(void* const* d_in, const int* in_sizes, int n_in,
                              void* d_out, int out_size, void* d_ws, size_t ws_size,
                              hipStream_t stream) {
  const float* x  = (const float*)d_in[0];
  const float* Wr = (const float*)d_in[1];
  const float* br = (const float*)d_in[2];
  const float* W1 = (const float*)d_in[3];
  const float* b1 = (const float*)d_in[4];
  const float* W2 = (const float*)d_in[5];
  const float* b2 = (const float*)d_in[6];

  char* ws = (char*)d_ws;
  unsigned short* xb    = (unsigned short*)(ws);               // [0,16M)  x bf16
  unsigned short* W1T   = (unsigned short*)(ws + (16u << 20)); // [16,32M) [8192][1024]
  unsigned short* W2T   = (unsigned short*)(ws + (32u << 20)); // [32,48M) [1024][8192]
  float*          gates = (float*)(ws + (48u << 20));          // [48M,+64K)
  unsigned short* hbuf  = (unsigned short*)(ws + (49u << 20)); // [49,177M) [8192][8192]
  float*          P1    = (float*)(ws);                        // reuses xb+W1T after GEMM1

  k_router<<<dim3(T_TOK / 4), dim3(256), 0, stream>>>(x, Wr, br, xb, gates);

  k_transpose<<<dim3(HDIM / 32, DDIM / 32, 2), dim3(256), 0, stream>>>(
      W1, W1T, DDIM, HDIM, DDIM, (size_t)DDIM * HDIM, (size_t)HDIM * DDIM);
  k_transpose<<<dim3(DDIM / 32, HDIM / 32, 2), dim3(256), 0, stream>>>(
      W2, W2T, HDIM, DDIM, KCAT, (size_t)HDIM * DDIM, (size_t)HDIM);

  // layer1: 8192x8192x1024 (experts concat over N), NT = 1024/32 = 32
  k_gemm2<32, 0><<<dim3(KCAT / 256, T_TOK / 256, 1), dim3(512), 0, stream>>>(
      xb, W1T, hbuf, nullptr, nullptr, b1, gates, DDIM, DDIM);

  // layer2: 8192x1024x8192, split-K=2 at expert boundary, NT = 4096/32 = 128
  k_gemm2<128, 1><<<dim3(DDIM / 256, T_TOK / 256, 2), dim3(512), 0, stream>>>(
      hbuf, W2T, nullptr, (float*)d_out, P1, nullptr, nullptr, KCAT, KCAT);

  k_combine<<<dim3(T_TOK * DDIM / 4 / 256), dim3(256), 0, stream>>>(
      P1, b2, gates, (float*)d_out);
}

// Round 12
// 322.020 us; speedup vs baseline: 9.5950x; 1.0106x over previous
//
#include <hip/hip_runtime.h>
#include <hip/hip_bf16.h>

#define T_TOK 8192
#define DDIM  1024
#define HDIM  4096
#define KCAT  8192   // 2*HDIM
#define NE    8

typedef __attribute__((ext_vector_type(8))) __bf16 bf16x8;
typedef __attribute__((ext_vector_type(4))) float  f32x4;

__device__ __forceinline__ unsigned short f2bf(float f) {
  union { float f; unsigned u; } v; v.f = f;
  unsigned r = v.u + 0x7fffu + ((v.u >> 16) & 1u);
  return (unsigned short)(r >> 16);
}

__device__ __forceinline__ void gl_lds16(const unsigned short* g, char* l) {
  __builtin_amdgcn_global_load_lds(
      (__attribute__((address_space(1))) const void*)g,
      (__attribute__((address_space(3))) void*)l,
      16, 0, 0);
}

// ---------------- router + x -> bf16 conversion ----------------
__global__ __launch_bounds__(256) void k_router(
    const float* __restrict__ x, const float* __restrict__ Wr,
    const float* __restrict__ br, unsigned short* __restrict__ xb,
    float* __restrict__ gates)
{
  const int lane = threadIdx.x & 63;
  const int wv   = threadIdx.x >> 6;
  const int t    = blockIdx.x * 4 + wv;
  const float* xr = x + (size_t)t * DDIM;
  unsigned short* xo = xb + (size_t)t * DDIM;

  float acc[NE];
#pragma unroll
  for (int e = 0; e < NE; ++e) acc[e] = 0.f;

#pragma unroll
  for (int i = 0; i < 4; ++i) {
    float4 v = *(const float4*)(xr + i * 256 + lane * 4);
    ushort4 o;
    o.x = f2bf(v.x); o.y = f2bf(v.y); o.z = f2bf(v.z); o.w = f2bf(v.w);
    *(ushort4*)(xo + i * 256 + lane * 4) = o;
    float vs[4] = {v.x, v.y, v.z, v.w};
#pragma unroll
    for (int j = 0; j < 4; ++j) {
      const float4* wr = (const float4*)(Wr + (size_t)(i * 256 + lane * 4 + j) * NE);
      float4 w0 = wr[0], w1 = wr[1];
      acc[0] += vs[j] * w0.x; acc[1] += vs[j] * w0.y;
      acc[2] += vs[j] * w0.z; acc[3] += vs[j] * w0.w;
      acc[4] += vs[j] * w1.x; acc[5] += vs[j] * w1.y;
      acc[6] += vs[j] * w1.z; acc[7] += vs[j] * w1.w;
    }
  }
#pragma unroll
  for (int e = 0; e < NE; ++e) {
#pragma unroll
    for (int s = 32; s > 0; s >>= 1) acc[e] += __shfl_xor(acc[e], s, 64);
  }
  if (lane == 0) {
    float lg[NE];
#pragma unroll
    for (int e = 0; e < NE; ++e) lg[e] = acc[e] + br[e];
    int a1 = 0; float m1 = lg[0];
#pragma unroll
    for (int e = 1; e < NE; ++e) if (lg[e] > m1) { m1 = lg[e]; a1 = e; }
    float m2 = -3.4e38f;
#pragma unroll
    for (int e = 0; e < NE; ++e) if (e != a1 && lg[e] > m2) m2 = lg[e];
    float g0 = 1.f / (1.f + expf(m2 - m1));
    gates[t * 2 + 0] = g0;
    gates[t * 2 + 1] = 1.f - g0;
  }
}

// ---------------- fp32 -> bf16 transpose ----------------
__global__ __launch_bounds__(256) void k_transpose(
    const float* __restrict__ in, unsigned short* __restrict__ out,
    int R, int C, int S, size_t inz, size_t outz)
{
  __shared__ float tile[32][33];
  in  += (size_t)blockIdx.z * inz;
  out += (size_t)blockIdx.z * outz;
  const int c0 = blockIdx.x * 32, r0 = blockIdx.y * 32;
  const int tx = threadIdx.x & 31, ty = threadIdx.x >> 5;
#pragma unroll
  for (int i = 0; i < 32; i += 8)
    tile[ty + i][tx] = in[(size_t)(r0 + ty + i) * C + (c0 + tx)];
  __syncthreads();
#pragma unroll
  for (int i = 0; i < 32; i += 8)
    out[(size_t)(c0 + ty + i) * S + (r0 + tx)] = f2bf(tile[tx][ty + i]);
}

// -------- register-pipelined 256x256 MFMA GEMM (BK=32, 1 barrier/phase) ----
// C[256x256] = A[M][KA]·B[N][KB]^T over K = NT*32 from koff = z*NT*32.
// 512 threads = 8 waves (2M x 4N), per-wave 128x64, 16x16x32 frags.
// LDS: 2 buffers x {A 16KiB, B 16KiB} = 64 KiB; tile t in buf[t&1].
// PIPELINE: MFMA(p) consumes frag regs READ IN PHASE p-1. Phase p:
//   vmcnt(0)            -> own stage(p+1) loads landed
//   s_barrier           -> tile p+1 certified in LDS (all waves)
//   12 ds_reads tile p+1 -> other reg set   (drain under MFMA below)
//   stage(p+2) -> buf[p&1]   (tile p's reads issued >=1 MFMA cluster ago
//                             before a barrier -> complete; no race)
//   sched_barrier(0); MFMA(p) on current set (compiler emits lgkmcnt(12))
// The 12 reads + 4 staging writes (~1412 cyc LDS port) overlap the 1242-cyc
// MFMA cluster instead of serializing with it (R3-R11's 2720-cyc phase).
template<int NT, int MODE>
__global__ __launch_bounds__(512) void k_gemmp(
    const unsigned short* __restrict__ A,
    const unsigned short* __restrict__ B,
    unsigned short* __restrict__ Hout,
    float* __restrict__ P0, float* __restrict__ P1,
    const float* __restrict__ bias,
    const float* __restrict__ gates,
    int KA, int KB)
{
  __shared__ __align__(16) char lds[2 * 32768];

  const int tid = threadIdx.x;
  const int l = tid & 63, g = (l >> 4), l15 = l & 15;
  const int w = tid >> 6;
  const int wm = w >> 2, wn = w & 3;

  // ---- XCD-chunked bijective swizzle (kept constant since R4) ----
  int bmIdx, bnIdx, bzIdx;
  {
    int lin = ((blockIdx.z * gridDim.y) + blockIdx.y) * gridDim.x + blockIdx.x;
    int xcd = lin & 7, slot = (lin >> 3) & 31;
    if (MODE == 0) {
      int r = lin >> 8;
      bmIdx = r * 8 + (slot >> 2);
      bnIdx = xcd * 4 + (slot & 3);
      bzIdx = 0;
    } else {
      bzIdx = xcd & 1;
      bmIdx = (xcd >> 1) * 8 + (slot >> 2);
      bnIdx = slot & 3;
    }
  }
  const int bn = bnIdx * 256;
  const int bm = bmIdx * 256;
  const int koff = bzIdx * (NT * 32);

  // staging: dest chunk tid = (row=tid>>2, c=tid&3); source chunk = c ^ ((row>>1)&3)
  const int srow = tid >> 2;
  const int sc = (tid & 3) ^ ((srow >> 1) & 3);
  const unsigned short* As = A + (size_t)(bm + srow) * KA + koff + sc * 8;
  const unsigned short* Bs = B + (size_t)(bn + srow) * KB + koff + sc * 8;

  auto stage = [&](int T, int reg) {  // reg: 0=A, 1=B; tile T = k [T*32, T*32+32)
    const unsigned short* src = (reg ? Bs : As) + T * 32;
    size_t rstride = (size_t)128 * (reg ? KB : KA);
    char* dst = lds + ((T & 1) << 15) + (reg << 14) + tid * 16;
    gl_lds16(src, dst);
    gl_lds16(src + rstride, dst + 8192);
  };

  // fragment LDS byte offsets within a 16 KiB region (rows: 64 B = 32 bf16 k)
  int aoff[2][4], boff[4];
#pragma unroll
  for (int mh = 0; mh < 2; ++mh)
#pragma unroll
    for (int mi = 0; mi < 4; ++mi) {
      int r = wm * 128 + mh * 64 + mi * 16 + l15;
      aoff[mh][mi] = r * 64 + ((g ^ ((r >> 1) & 3)) * 16);
    }
#pragma unroll
  for (int nj = 0; nj < 4; ++nj) {
    int r = wn * 64 + nj * 16 + l15;
    boff[nj] = r * 64 + ((g ^ ((r >> 1) & 3)) * 16);
  }

  f32x4 acc[8][4];
#pragma unroll
  for (int i = 0; i < 8; ++i)
#pragma unroll
    for (int j = 0; j < 4; ++j) acc[i][j] = (f32x4){0.f, 0.f, 0.f, 0.f};

  bf16x8 RA[12], RB[12];   // two fragment sets; [0..3]=B, [4..11]=A (all literal-indexed)

#define READS(R, b) do {                                                       \
    const char* Ar_ = lds + ((b) << 15);                                       \
    const char* Br_ = Ar_ + 16384;                                             \
    R[0]  = *(const bf16x8*)(Br_ + boff[0]);                                   \
    R[1]  = *(const bf16x8*)(Br_ + boff[1]);                                   \
    R[2]  = *(const bf16x8*)(Br_ + boff[2]);                                   \
    R[3]  = *(const bf16x8*)(Br_ + boff[3]);                                   \
    R[4]  = *(const bf16x8*)(Ar_ + aoff[0][0]);                                \
    R[5]  = *(const bf16x8*)(Ar_ + aoff[0][1]);                                \
    R[6]  = *(const bf16x8*)(Ar_ + aoff[0][2]);                                \
    R[7]  = *(const bf16x8*)(Ar_ + aoff[0][3]);                                \
    R[8]  = *(const bf16x8*)(Ar_ + aoff[1][0]);                                \
    R[9]  = *(const bf16x8*)(Ar_ + aoff[1][1]);                                \
    R[10] = *(const bf16x8*)(Ar_ + aoff[1][2]);                                \
    R[11] = *(const bf16x8*)(Ar_ + aoff[1][3]);                                \
  } while (0)

#define MFMA32(R)                                                              \
    acc[0][0] = __builtin_amdgcn_mfma_f32_16x16x32_bf16(R[4],  R[0], acc[0][0], 0,0,0); \
    acc[0][1] = __builtin_amdgcn_mfma_f32_16x16x32_bf16(R[4],  R[1], acc[0][1], 0,0,0); \
    acc[0][2] = __builtin_amdgcn_mfma_f32_16x16x32_bf16(R[4],  R[2], acc[0][2], 0,0,0); \
    acc[0][3] = __builtin_amdgcn_mfma_f32_16x16x32_bf16(R[4],  R[3], acc[0][3], 0,0,0); \
    acc[1][0] = __builtin_amdgcn_mfma_f32_16x16x32_bf16(R[5],  R[0], acc[1][0], 0,0,0); \
    acc[1][1] = __builtin_amdgcn_mfma_f32_16x16x32_bf16(R[5],  R[1], acc[1][1], 0,0,0); \
    acc[1][2] = __builtin_amdgcn_mfma_f32_16x16x32_bf16(R[5],  R[2], acc[1][2], 0,0,0); \
    acc[1][3] = __builtin_amdgcn_mfma_f32_16x16x32_bf16(R[5],  R[3], acc[1][3], 0,0,0); \
    acc[2][0] = __builtin_amdgcn_mfma_f32_16x16x32_bf16(R[6],  R[0], acc[2][0], 0,0,0); \
    acc[2][1] = __builtin_amdgcn_mfma_f32_16x16x32_bf16(R[6],  R[1], acc[2][1], 0,0,0); \
    acc[2][2] = __builtin_amdgcn_mfma_f32_16x16x32_bf16(R[6],  R[2], acc[2][2], 0,0,0); \
    acc[2][3] = __builtin_amdgcn_mfma_f32_16x16x32_bf16(R[6],  R[3], acc[2][3], 0,0,0); \
    acc[3][0] = __builtin_amdgcn_mfma_f32_16x16x32_bf16(R[7],  R[0], acc[3][0], 0,0,0); \
    acc[3][1] = __builtin_amdgcn_mfma_f32_16x16x32_bf16(R[7],  R[1], acc[3][1], 0,0,0); \
    acc[3][2] = __builtin_amdgcn_mfma_f32_16x16x32_bf16(R[7],  R[2], acc[3][2], 0,0,0); \
    acc[3][3] = __builtin_amdgcn_mfma_f32_16x16x32_bf16(R[7],  R[3], acc[3][3], 0,0,0); \
    acc[4][0] = __builtin_amdgcn_mfma_f32_16x16x32_bf16(R[8],  R[0], acc[4][0], 0,0,0); \
    acc[4][1] = __builtin_amdgcn_mfma_f32_16x16x32_bf16(R[8],  R[1], acc[4][1], 0,0,0); \
    acc[4][2] = __builtin_amdgcn_mfma_f32_16x16x32_bf16(R[8],  R[2], acc[4][2], 0,0,0); \
    acc[4][3] = __builtin_amdgcn_mfma_f32_16x16x32_bf16(R[8],  R[3], acc[4][3], 0,0,0); \
    acc[5][0] = __builtin_amdgcn_mfma_f32_16x16x32_bf16(R[9],  R[0], acc[5][0], 0,0,0); \
    acc[5][1] = __builtin_amdgcn_mfma_f32_16x16x32_bf16(R[9],  R[1], acc[5][1], 0,0,0); \
    acc[5][2] = __builtin_amdgcn_mfma_f32_16x16x32_bf16(R[9],  R[2], acc[5][2], 0,0,0); \
    acc[5][3] = __builtin_amdgcn_mfma_f32_16x16x32_bf16(R[9],  R[3], acc[5][3], 0,0,0); \
    acc[6][0] = __builtin_amdgcn_mfma_f32_16x16x32_bf16(R[10], R[0], acc[6][0], 0,0,0); \
    acc[6][1] = __builtin_amdgcn_mfma_f32_16x16x32_bf16(R[10], R[1], acc[6][1], 0,0,0); \
    acc[6][2] = __builtin_amdgcn_mfma_f32_16x16x32_bf16(R[10], R[2], acc[6][2], 0,0,0); \
    acc[6][3] = __builtin_amdgcn_mfma_f32_16x16x32_bf16(R[10], R[3], acc[6][3], 0,0,0); \
    acc[7][0] = __builtin_amdgcn_mfma_f32_16x16x32_bf16(R[11], R[0], acc[7][0], 0,0,0); \
    acc[7][1] = __builtin_amdgcn_mfma_f32_16x16x32_bf16(R[11], R[1], acc[7][1], 0,0,0); \
    acc[7][2] = __builtin_amdgcn_mfma_f32_16x16x32_bf16(R[11], R[2], acc[7][2], 0,0,0); \
    acc[7][3] = __builtin_amdgcn_mfma_f32_16x16x32_bf16(R[11], R[3], acc[7][3], 0,0,0);

  // PH: one phase. RD = set receiving reads of tile p+1 (from buf RDB);
  //     MF = set consumed by MFMA (tile p). Optional stage of tile p+2.
#define PH(RD, RDB, MF, DOSTG, STGT) do {                                      \
    asm volatile("s_waitcnt vmcnt(0)" ::: "memory");                           \
    __builtin_amdgcn_s_barrier();                                              \
    READS(RD, RDB);                                                            \
    if (DOSTG) { stage((STGT), 0); stage((STGT), 1); }                         \
    asm volatile("" ::: "memory");                                             \
    __builtin_amdgcn_sched_barrier(0);                                         \
    __builtin_amdgcn_s_setprio(1);                                             \
    MFMA32(MF)                                                                 \
    __builtin_amdgcn_s_setprio(0);                                             \
  } while (0)

  // prologue: tile0 staged+certified; reads(0) -> RA; stage(1)
  stage(0, 0); stage(0, 1);
  asm volatile("s_waitcnt vmcnt(0)" ::: "memory");
  __builtin_amdgcn_s_barrier();
  READS(RA, 0);
  stage(1, 0); stage(1, 1);

  // main loop: phases p=0..NT-3 (pairs); NT even >= 4
  for (int tt = 0; tt < NT / 2 - 1; ++tt) {
    PH(RB, 1, RA, true, 2 * tt + 2);   // phase 2tt:   MFMA tile 2tt,   read 2tt+1, stage 2tt+2
    PH(RA, 0, RB, true, 2 * tt + 3);   // phase 2tt+1: MFMA tile 2tt+1, read 2tt+2, stage 2tt+3
  }
  // phase NT-2: MFMA tile NT-2, read tile NT-1 (buf1), no stage
  PH(RB, 1, RA, false, 0);
  // phase NT-1: MFMA tile NT-1 (reads complete; compiler waits)
  __builtin_amdgcn_s_setprio(1);
  MFMA32(RB)
  __builtin_amdgcn_s_setprio(0);
#undef PH
#undef MFMA32
#undef READS

  // epilogue; C/D map: col = l&15, row = (l>>4)*4 + rr
  if constexpr (MODE == 0) {
    const int ge = bn >> 12;
    float bcol[4];
#pragma unroll
    for (int nj = 0; nj < 4; ++nj) bcol[nj] = bias[bn + wn * 64 + nj * 16 + l15];
#pragma unroll
    for (int mi = 0; mi < 8; ++mi) {
#pragma unroll
      for (int rr = 0; rr < 4; ++rr) {
        int row = bm + wm * 128 + mi * 16 + g * 4 + rr;
        float gate = gates[row * 2 + ge];
        size_t rb = (size_t)row * KCAT + bn + wn * 64 + l15;
#pragma unroll
        for (int nj = 0; nj < 4; ++nj) {
          float v = acc[mi][nj][rr] + bcol[nj];
          Hout[rb + nj * 16] = f2bf(fmaxf(v, 0.f) * gate);
        }
      }
    }
  } else {
    float* P = bzIdx ? P1 : P0;
#pragma unroll
    for (int mi = 0; mi < 8; ++mi) {
#pragma unroll
      for (int rr = 0; rr < 4; ++rr) {
        int row = bm + wm * 128 + mi * 16 + g * 4 + rr;
        size_t rb = (size_t)row * DDIM + bn + wn * 64 + l15;
#pragma unroll
        for (int nj = 0; nj < 4; ++nj) P[rb + nj * 16] = acc[mi][nj][rr];
      }
    }
  }
}

// ---------------- combine: out = p0 + p1 + g0*b2[0] + g1*b2[1] ----------------
__global__ __launch_bounds__(256) void k_combine(
    const float* __restrict__ P1, const float* __restrict__ b2,
    const float* __restrict__ gates, float* __restrict__ O)
{
  size_t i = ((size_t)blockIdx.x * 256 + threadIdx.x) * 4;
  int row = (int)(i >> 10), d = (int)(i & 1023);
  float g0 = gates[row * 2], g1 = gates[row * 2 + 1];
  float4 p0 = *(const float4*)(O + i);
  float4 p1 = *(const float4*)(P1 + i);
  float4 ba = *(const float4*)(b2 + d);
  float4 bb = *(const float4*)(b2 + DDIM + d);
  float4 r;
  r.x = p0.x + p1.x + g0 * ba.x + g1 * bb.x;
  r.y = p0.y + p1.y + g0 * ba.y + g1 * bb.y;
  r.z = p0.z + p1.z + g0 * ba.z + g1 * bb.z;
  r.w = p0.w + p1.w + g0 * ba.w + g1 * bb.w;
  *(float4*)(O + i) = r;
}

extern "C" void kernel_launch(void* const* d_in, const int* in_sizes, int n_in,
                              void* d_out, int out_size, void* d_ws, size_t ws_size,
                              hipStream_t stream) {
  const float* x  = (const float*)d_in[0];
  const float* Wr = (const float*)d_in[1];
  const float* br = (const float*)d_in[2];
  const float* W1 = (const float*)d_in[3];
  const float* b1 = (const float*)d_in[4];
  const float* W2 = (const float*)d_in[5];
  const float* b2 = (const float*)d_in[6];

  char* ws = (char*)d_ws;
  unsigned short* xb    = (unsigned short*)(ws);               // [0,16M)  x bf16
  unsigned short* W1T   = (unsigned short*)(ws + (16u << 20)); // [16,32M) [8192][1024]
  unsigned short* W2T   = (unsigned short*)(ws + (32u << 20)); // [32,48M) [1024][8192]
  float*          gates = (float*)(ws + (48u << 20));          // [48M,+64K)
  unsigned short* hbuf  = (unsigned short*)(ws + (49u << 20)); // [49,177M) [8192][8192]
  float*          P1    = (float*)(ws);                        // reuses xb+W1T after GEMM1

  k_router<<<dim3(T_TOK / 4), dim3(256), 0, stream>>>(x, Wr, br, xb, gates);

  k_transpose<<<dim3(HDIM / 32, DDIM / 32, 2), dim3(256), 0, stream>>>(
      W1, W1T, DDIM, HDIM, DDIM, (size_t)DDIM * HDIM, (size_t)HDIM * DDIM);
  k_transpose<<<dim3(DDIM / 32, HDIM / 32, 2), dim3(256), 0, stream>>>(
      W2, W2T, HDIM, DDIM, KCAT, (size_t)HDIM * DDIM, (size_t)HDIM);

  // layer1: 8192x8192x1024 (experts concat over N), NT = 1024/32 = 32
  k_gemmp<32, 0><<<dim3(KCAT / 256, T_TOK / 256, 1), dim3(512), 0, stream>>>(
      xb, W1T, hbuf, nullptr, nullptr, b1, gates, DDIM, DDIM);

  // layer2: 8192x1024x8192, split-K=2 at expert boundary, NT = 4096/32 = 128
  k_gemmp<128, 1><<<dim3(DDIM / 256, T_TOK / 256, 2), dim3(512), 0, stream>>>(
      hbuf, W2T, nullptr, (float*)d_out, P1, nullptr, nullptr, KCAT, KCAT);

  k_combine<<<dim3(T_TOK * DDIM / 4 / 256), dim3(256), 0, stream>>>(
      P1, b2, gates, (float*)d_out);
}